// Round 3
// baseline (155.917 us; speedup 1.0000x reference)
//
#include <hip/hip_runtime.h>
#include <hip/hip_bf16.h>

// ---------------------------------------------------------------------------
// Additive attention weights:
//   logits[b,i,j] = sum_d Wl[d]*tanh(aq[b,i,d] + ak[b,j,d] + bc[d]) + bl
//   out = softmax_j(mask ? logits : -inf)
// Folds:
//   tanh(x) = 1 - 2/(2^{Cx}+1), C = 2*log2(e); uniform-in-j terms cancel.
//   l_j = sum_d (-2 Wl_d) * rcp(E_d * G_jd + 1),
//   E = exp2(C*(aq+bc))  [per (b,i) row],  G = exp2(C*ak)  [per (b,j)]
//   -> inner loop has ONE transcendental (rcp) per element instead of two.
// GEMM chains fused into one dispatch:
//   chain 0: q2 = (query@Wq.T+bq)/sqrt(D) -> E = exp2(C*(q2@Wc_l.T + bc))
//   chain 1: k2 = key@Wk.T+bk             -> G = exp2(C*(k2@Wc_r.T))
// Softmax max-subtraction dropped: |l| <= 2*sum|Wl| ~ 17 -> exp2 args safe.
// ---------------------------------------------------------------------------

#define LOG2E     1.4426950408889634f
#define TWO_LOG2E 2.8853900817779268f
#define INV_SQRTD 0.04419417382415922f   // 1/sqrt(512)

typedef __attribute__((ext_vector_type(8))) short v8s;   // 8 bf16
typedef __attribute__((ext_vector_type(4))) float v4f;   // MFMA accumulator

#if __has_builtin(__builtin_amdgcn_exp2f)
#define EXP2(x) __builtin_amdgcn_exp2f(x)
#else
#define EXP2(x) exp2f(x)
#endif
#if __has_builtin(__builtin_amdgcn_rcpf)
#define RCP(x) __builtin_amdgcn_rcpf(x)
#else
#define RCP(x) (1.0f/(x))
#endif

__device__ inline unsigned bfpair(float a, float b) {   // -> v_cvt_pk_bf16_f32
  __hip_bfloat162 h = __float22bfloat162_rn(make_float2(a, b));
  return *reinterpret_cast<unsigned*>(&h);
}
__device__ inline v8s pack8(float4 a, float4 b) {
  union { unsigned u[4]; v8s v; } r;
  r.u[0] = bfpair(a.x, a.y); r.u[1] = bfpair(a.z, a.w);
  r.u[2] = bfpair(b.x, b.y); r.u[3] = bfpair(b.z, b.w);
  return r.v;
}

// ---------------------------------------------------------------------------
// K_A: fused two-stage projection. grid (16 m-blocks, 2 n-halves, 2 chains),
// 256 threads / 4 waves. Stage 1: 32x512 projection block, MFMA fragments
// loaded directly from global (f32 -> bf16 in-reg), acc in VGPR. Rounded to
// bf16 into XOR-swizzled LDS. Stage 2: 32x256 half of the Wc product, A-frags
// from LDS, B-frags direct from global; epilogue applies exp2 and stores E/G.
// ---------------------------------------------------------------------------
__global__ __launch_bounds__(256) void fused_proj(
    const float* __restrict__ query, const float* __restrict__ key,
    const float* __restrict__ Wq, const float* __restrict__ bq,
    const float* __restrict__ Wk, const float* __restrict__ bk,
    const float* __restrict__ Wc, const float* __restrict__ bc,
    float* __restrict__ E, float* __restrict__ G)
{
  const int mb = blockIdx.x;          // 16 row-blocks of 32
  const int h  = blockIdx.y;          // stage-2 n-half
  const int c  = blockIdx.z;          // chain: 0=query/E, 1=key/G
  const int tid = threadIdx.x;
  const int lane = tid & 63;
  const int w = tid >> 6;

  const float* A  = c ? key : query;
  const float* W1 = c ? Wk : Wq;
  const float* b1 = c ? bk : bq;
  const float  s1 = c ? 1.0f : INV_SQRTD;
  const float* W2 = Wc + (c ? 512 : 0);   // Wc row length 1024

  __shared__ __align__(16) unsigned char q2s[32 * 1024];  // [32][512] bf16, swizzled

  const int fr  = lane & 15;           // fragment row
  const int fko = (lane >> 4) * 8;     // fragment k offset (elements)
  const int m0  = mb * 32;

  // ---- stage 1: proj_blk[32][512] = (A_blk @ W1.T + b1) * s1 ----
  v4f acc[2][8];
#pragma unroll
  for (int mt = 0; mt < 2; ++mt)
#pragma unroll
    for (int nt = 0; nt < 8; ++nt) acc[mt][nt] = (v4f){0.f, 0.f, 0.f, 0.f};

  const float* arow0 = A + (m0 + fr) * 512 + fko;
  const float* arow1 = arow0 + 16 * 512;
  const float* brow  = W1 + (w * 128 + fr) * 512 + fko;

  for (int kt = 0; kt < 16; ++kt) {
    const int k0 = kt * 32;
    float4 a00 = *(const float4*)(arow0 + k0);
    float4 a01 = *(const float4*)(arow0 + k0 + 4);
    float4 a10 = *(const float4*)(arow1 + k0);
    float4 a11 = *(const float4*)(arow1 + k0 + 4);
    v8s am0 = pack8(a00, a01);
    v8s am1 = pack8(a10, a11);
#pragma unroll
    for (int nt = 0; nt < 8; ++nt) {
      const float* bp = brow + nt * (16 * 512) + k0;
      float4 b0 = *(const float4*)(bp);
      float4 b1v = *(const float4*)(bp + 4);
      v8s bf = pack8(b0, b1v);
      acc[0][nt] = __builtin_amdgcn_mfma_f32_16x16x32_bf16(am0, bf, acc[0][nt], 0, 0, 0);
      acc[1][nt] = __builtin_amdgcn_mfma_f32_16x16x32_bf16(am1, bf, acc[1][nt], 0, 0, 0);
    }
  }

  // stage-1 epilogue -> swizzled bf16 LDS
  {
    const int rbase = (lane >> 4) * 4;
#pragma unroll
    for (int nt = 0; nt < 8; ++nt) {
      const int n1 = w * 128 + nt * 16 + fr;
      const float bb = b1[n1];
#pragma unroll
      for (int mt = 0; mt < 2; ++mt) {
#pragma unroll
        for (int r = 0; r < 4; ++r) {
          const int row = mt * 16 + rbase + r;
          const float v = (acc[mt][nt][r] + bb) * s1;
          const int addr = (row * 1024 + n1 * 2) ^ ((row & 7) << 4);
          *(__hip_bfloat16*)(q2s + addr) = __float2bfloat16(v);
        }
      }
    }
  }
  __syncthreads();

  // ---- stage 2: out_half[32][256] = proj_blk @ W2half.T ----
  v4f acc2[2][4];
#pragma unroll
  for (int mt = 0; mt < 2; ++mt)
#pragma unroll
    for (int nt = 0; nt < 4; ++nt) acc2[mt][nt] = (v4f){0.f, 0.f, 0.f, 0.f};

  const float* w2row = W2 + (h * 256 + w * 64 + fr) * 1024 + fko;
  const int a0r = fr, a1r = fr + 16;

  for (int kt = 0; kt < 16; ++kt) {
    const int kb = kt * 64 + fko * 2;   // byte offset into a 1024B LDS row
    v8s am0 = *(const v8s*)(q2s + ((a0r * 1024 + kb) ^ ((a0r & 7) << 4)));
    v8s am1 = *(const v8s*)(q2s + ((a1r * 1024 + kb) ^ ((a1r & 7) << 4)));
    const int k0 = kt * 32;
#pragma unroll
    for (int nt = 0; nt < 4; ++nt) {
      const float* bp = w2row + nt * (16 * 1024) + k0;
      float4 b0 = *(const float4*)(bp);
      float4 b1v = *(const float4*)(bp + 4);
      v8s bf = pack8(b0, b1v);
      acc2[0][nt] = __builtin_amdgcn_mfma_f32_16x16x32_bf16(am0, bf, acc2[0][nt], 0, 0, 0);
      acc2[1][nt] = __builtin_amdgcn_mfma_f32_16x16x32_bf16(am1, bf, acc2[1][nt], 0, 0, 0);
    }
  }

  // stage-2 epilogue: E = exp2(C*(x + bc)) row-major; G = exp2(C*x) interleaved
  {
    const int rbase = (lane >> 4) * 4;
#pragma unroll
    for (int nt = 0; nt < 4; ++nt) {
      const int n2 = h * 256 + w * 64 + nt * 16 + fr;
      const float bb = c ? 0.f : bc[n2];
#pragma unroll
      for (int mt = 0; mt < 2; ++mt) {
#pragma unroll
        for (int r = 0; r < 4; ++r) {
          const int m = m0 + mt * 16 + rbase + r;
          const float v = EXP2(TWO_LOG2E * (acc2[mt][nt][r] + bb));
          if (c == 0) E[m * 512 + n2] = v;
          else G[(m >> 8) * 131072 + (n2 >> 2) * 1024 + (m & 255) * 4 + (n2 & 3)] = v;
        }
      }
    }
  }
}

// ---------------------------------------------------------------------------
// K_B: one WG per (b,i) row; thread = j. l_j = sum_d w2_d*rcp(E_d*G_jd + 1),
// masked softmax (no max-sub needed: |l| <= 2*sum|Wl| ~ 17). Mask element
// width detected inline by wave 0 (words of a 0/1 mask are {0,1,0x3F800000}).
// ---------------------------------------------------------------------------
__global__ __launch_bounds__(256) void attn_sm(
    const float* __restrict__ E, const float* __restrict__ G,
    const void* __restrict__ maskp, const float* __restrict__ Wl,
    float* __restrict__ out)
{
  const int bx = blockIdx.x;   // b*256 + i
  const int j  = threadIdx.x;  // kv index

  __shared__ float2 cw[512];
  __shared__ float red[4];
  __shared__ int sflag;

  if (j < 64) {
    unsigned wrd = ((const unsigned*)maskp)[j];
    bool ok = (wrd == 0u) | (wrd == 1u) | (wrd == 0x3F800000u);
    unsigned long long bl = __ballot(ok);
    if (j == 0) sflag = (~bl == 0ull) ? 0 : 1;   // 1 = byte mask
  }
  for (int dd = j; dd < 512; dd += 256)
    cw[dd] = make_float2(E[bx * 512 + dd], -2.f * Wl[dd]);
  __syncthreads();

  const float* g = G + (bx >> 8) * 131072 + j * 4;
  float a0 = 0.f, a1 = 0.f, a2 = 0.f, a3 = 0.f;
#pragma unroll 8
  for (int db = 0; db < 128; ++db) {
    float4 v = *(const float4*)(g + db * 1024);
    float2 p0 = cw[db * 4 + 0], p1 = cw[db * 4 + 1];
    float2 p2 = cw[db * 4 + 2], p3 = cw[db * 4 + 3];
    a0 += p0.y * RCP(__builtin_fmaf(p0.x, v.x, 1.f));
    a1 += p1.y * RCP(__builtin_fmaf(p1.x, v.y, 1.f));
    a2 += p2.y * RCP(__builtin_fmaf(p2.x, v.z, 1.f));
    a3 += p3.y * RCP(__builtin_fmaf(p3.x, v.w, 1.f));
  }
  float l = (a0 + a1) + (a2 + a3);

  const int midx = bx * 256 + j;
  const int mv = sflag ? (int)((const unsigned char*)maskp)[midx]
                       : ((const int*)maskp)[midx];
  const bool msk = (mv != 0);
  const int any = __syncthreads_or(msk ? 1 : 0);
  const bool use = msk || (any == 0);   // fully-masked row -> unmask all

  float p = use ? EXP2(l * LOG2E) : 0.f;
  float s = p;
#pragma unroll
  for (int o = 32; o > 0; o >>= 1) s += __shfl_xor(s, o);
  if ((j & 63) == 0) red[j >> 6] = s;
  __syncthreads();
  const float S = (red[0] + red[1]) + (red[2] + red[3]);

  out[midx] = p * RCP(S);
}

extern "C" void kernel_launch(void* const* d_in, const int* in_sizes, int n_in,
                              void* d_out, int out_size, void* d_ws, size_t ws_size,
                              hipStream_t stream) {
  const float* key   = (const float*)d_in[0];
  const float* query = (const float*)d_in[1];
  // d_in[2] (value), d_in[6] (W_v), d_in[7] (b_v), d_in[13] (b_l) unused.
  const void*  mask  = d_in[3];
  const float* W_k   = (const float*)d_in[4];
  const float* b_k   = (const float*)d_in[5];
  const float* W_q   = (const float*)d_in[8];
  const float* b_q   = (const float*)d_in[9];
  const float* W_c   = (const float*)d_in[10];
  const float* b_c   = (const float*)d_in[11];
  const float* W_l   = (const float*)d_in[12];

  float* ws = (float*)d_ws;
  float* E  = ws;             // [512][512] f32: exp2(C*(aq+bc)), row = b*256+i
  float* G  = ws + 262144;    // [2][128][256][4] f32: exp2(C*ak), d-interleaved

  fused_proj<<<dim3(16, 2, 2), 256, 0, stream>>>(query, key, W_q, b_q, W_k, b_k,
                                                 W_c, b_c, E, G);
  attn_sm<<<512, 256, 0, stream>>>(E, G, mask, W_l, (float*)d_out);
}

// Round 4
// 119.142 us; speedup vs baseline: 1.3087x; 1.3087x over previous
//
#include <hip/hip_runtime.h>
#include <hip/hip_bf16.h>

// ---------------------------------------------------------------------------
// Additive attention weights:
//   logits[b,i,j] = sum_d Wl[d]*tanh(aq[b,i,d] + ak[b,j,d] + bc[d]) + bl
//   out = softmax_j(mask ? logits : -inf)
// Folds:
//   tanh(x) = 1 - 2/(2^{Cx}+1), C = 2*log2(e); uniform-in-j terms cancel:
//   l_j = sum_d (-2 Wl_d) * rcp(E_d * G_jd + 1)
//   E = exp2(C*(aq+bc)) [per (b,i)], G = exp2(C*ak) [per (b,j)]
//   -> ONE transcendental per (i,j,d) element instead of two.
// Pipeline (3 dispatches):
//   gemm_bt z={q2,k2}:  q2=(query@Wq.T+bq)/sqrt(D), k2=key@Wk.T+bk
//   gemm_bt z={E,G}:    E=exp2(C*(q2@Wc_l.T+bc)), G=exp2(C*(k2@Wc_r.T))
//   attn_sm: l_j + masked softmax (no max-sub: |l| <= 2*sum|Wl| ~ 17).
// Round-3 lesson: fused direct-from-global MFMA was latency-bound (56us,
// 1% MfmaUtil) -> back to staged/coalesced round-1 GEMM + folded epilogues.
// ---------------------------------------------------------------------------

#define LOG2E     1.4426950408889634f
#define TWO_LOG2E 2.8853900817779268f
#define INV_SQRTD 0.04419417382415922f   // 1/sqrt(512)

typedef __attribute__((ext_vector_type(8))) short v8s;   // 8 bf16
typedef __attribute__((ext_vector_type(4))) float v4f;   // MFMA accumulator

#if __has_builtin(__builtin_amdgcn_exp2f)
#define EXP2(x) __builtin_amdgcn_exp2f(x)
#else
#define EXP2(x) exp2f(x)
#endif
#if __has_builtin(__builtin_amdgcn_rcpf)
#define RCP(x) __builtin_amdgcn_rcpf(x)
#else
#define RCP(x) (1.0f/(x))
#endif

__device__ inline unsigned cvt2bf(float a, float b) {  // RNE f32->bf16 pair
  unsigned ua = __float_as_uint(a);
  unsigned ub = __float_as_uint(b);
  ua = (ua + 0x7FFFu + ((ua >> 16) & 1u)) >> 16;
  ub = (ub + 0x7FFFu + ((ub >> 16) & 1u)) >> 16;
  return ua | (ub << 16);
}

// ---------------------------------------------------------------------------
// C = post(A @ W.T + bias) * scale, M=N=K=512, f32 in/out, bf16 MFMA.
// Two independent GEMMs per launch via blockIdx.z. BM=32, BN=64, BK=64,
// 256 threads (4 waves), grid 16x8x2 = 512 WGs total (1 WG/CU per z-slice).
// em!=0: v = exp2(v) before store. mode 1: d-interleaved G layout
// [b][d/4][j][4] so attn_sm reads a coalesced float4 per j.
// Staging loads for tile kt+1 are issued before the MFMA phase of tile kt.
// ---------------------------------------------------------------------------
__global__ __launch_bounds__(256) void gemm_bt(
    const float* __restrict__ A0, const float* __restrict__ W0, const float* __restrict__ b0,
    float s0, float* __restrict__ o0, int mode0, int ldw0, int em0,
    const float* __restrict__ A1, const float* __restrict__ W1, const float* __restrict__ b1,
    float s1, float* __restrict__ o1, int mode1, int ldw1, int em1)
{
  const int z = blockIdx.z;
  const float* A    = z ? A1 : A0;
  const float* W    = z ? W1 : W0;
  const float* bias = z ? b1 : b0;
  const float scale = z ? s1 : s0;
  float* out        = z ? o1 : o0;
  const int mode    = z ? mode1 : mode0;
  const int ldw     = z ? ldw1 : ldw0;
  const int em      = z ? em1 : em0;

  const int m0 = blockIdx.x * 32;
  const int n0 = blockIdx.y * 64;
  const int tid = threadIdx.x;
  const int lane = tid & 63;
  const int wv = tid >> 6;

  // A: [32][64] bf16 (128B rows) @0 ; B: [64][64] bf16 @4096. XOR-swizzled.
  __shared__ __align__(16) unsigned char smem[12288];

  const int ar  = tid >> 3;  // A stage row 0..31
  const int akg = tid & 7;   // 8-elem k-group
  const int br  = tid >> 2;  // B stage row 0..63
  const int bq  = tid & 3;   // 16-elem k-group

  const int fr = lane & 15;            // frag row within 16
  const int fk = (lane >> 4) * 16;     // frag k byte offset within 32-k slice

  v4f acc0 = {0.f, 0.f, 0.f, 0.f};
  v4f acc1 = {0.f, 0.f, 0.f, 0.f};

  const float* apb = A + (m0 + ar) * 512 + akg * 8;
  const float* bpb = W + (n0 + br) * ldw + bq * 16;

  // prefetch tile 0
  float4 av0 = *(const float4*)(apb);
  float4 av1 = *(const float4*)(apb + 4);
  float4 bv0 = *(const float4*)(bpb);
  float4 bv1 = *(const float4*)(bpb + 4);
  float4 bv2 = *(const float4*)(bpb + 8);
  float4 bv3 = *(const float4*)(bpb + 12);

  for (int kt = 0; kt < 8; ++kt) {
    __syncthreads();  // previous iteration's frag reads done
    {
      int addr = (ar * 128 + akg * 16) ^ ((ar & 7) << 4);
      *(uint4*)(smem + addr) = make_uint4(cvt2bf(av0.x, av0.y), cvt2bf(av0.z, av0.w),
                                          cvt2bf(av1.x, av1.y), cvt2bf(av1.z, av1.w));
      int base = br * 128 + bq * 32;
      int a1 = 4096 + ((base)      ^ ((br & 7) << 4));
      int a2 = 4096 + ((base + 16) ^ ((br & 7) << 4));
      *(uint4*)(smem + a1) = make_uint4(cvt2bf(bv0.x, bv0.y), cvt2bf(bv0.z, bv0.w),
                                        cvt2bf(bv1.x, bv1.y), cvt2bf(bv1.z, bv1.w));
      *(uint4*)(smem + a2) = make_uint4(cvt2bf(bv2.x, bv2.y), cvt2bf(bv2.z, bv2.w),
                                        cvt2bf(bv3.x, bv3.y), cvt2bf(bv3.z, bv3.w));
    }
    __syncthreads();

    if (kt < 7) {   // issue next tile's loads; they drain under MFMA + barrier
      const int k0 = (kt + 1) * 64;
      av0 = *(const float4*)(apb + k0);
      av1 = *(const float4*)(apb + k0 + 4);
      bv0 = *(const float4*)(bpb + k0);
      bv1 = *(const float4*)(bpb + k0 + 4);
      bv2 = *(const float4*)(bpb + k0 + 8);
      bv3 = *(const float4*)(bpb + k0 + 12);
    }

#pragma unroll
    for (int ks = 0; ks < 2; ++ks) {
      const int kb = ks * 64 + fk;
      const int rowb = wv * 16 + fr;
      int ra0 = ((fr)      * 128 + kb) ^ ((fr & 7) << 4);
      int ra1 = ((fr | 16) * 128 + kb) ^ ((fr & 7) << 4);
      int rb  = 4096 + ((rowb * 128 + kb) ^ ((rowb & 7) << 4));
      v8s a0 = *(const v8s*)(smem + ra0);
      v8s a1 = *(const v8s*)(smem + ra1);
      v8s b  = *(const v8s*)(smem + rb);
      acc0 = __builtin_amdgcn_mfma_f32_16x16x32_bf16(a0, b, acc0, 0, 0, 0);
      acc1 = __builtin_amdgcn_mfma_f32_16x16x32_bf16(a1, b, acc1, 0, 0, 0);
    }
  }

  const int n = n0 + wv * 16 + (lane & 15);
  const int mbase = m0 + (lane >> 4) * 4;
  const float bn = bias ? bias[n] : 0.f;
#pragma unroll
  for (int r = 0; r < 4; ++r) {
    int m  = mbase + r;
    int m2 = m + 16;
    float v0 = (acc0[r] + bn) * scale;
    float v1 = (acc1[r] + bn) * scale;
    if (em) { v0 = EXP2(v0); v1 = EXP2(v1); }
    if (mode == 0) {
      out[m * 512 + n]  = v0;
      out[m2 * 512 + n] = v1;
    } else {
      out[(m  >> 8) * 131072 + (n >> 2) * 1024 + (m  & 255) * 4 + (n & 3)] = v0;
      out[(m2 >> 8) * 131072 + (n >> 2) * 1024 + (m2 & 255) * 4 + (n & 3)] = v1;
    }
  }
}

// ---------------------------------------------------------------------------
// attn_sm: one WG per (b,i) row; thread = j. l_j = sum_d w2_d*rcp(E_d*G_jd+1),
// masked softmax (no max-sub: |l| <= 2*sum|Wl| ~ 17). Mask element width
// detected inline by wave 0 (i32/f32 words of a 0/1 mask are {0,1,0x3F800000}).
// ---------------------------------------------------------------------------
__global__ __launch_bounds__(256) void attn_sm(
    const float* __restrict__ E, const float* __restrict__ G,
    const void* __restrict__ maskp, const float* __restrict__ Wl,
    float* __restrict__ out)
{
  const int bx = blockIdx.x;   // b*256 + i
  const int j  = threadIdx.x;  // kv index

  __shared__ float2 cw[512];
  __shared__ float red[4];
  __shared__ int sflag;

  if (j < 64) {
    unsigned wrd = ((const unsigned*)maskp)[j];
    bool ok = (wrd == 0u) | (wrd == 1u) | (wrd == 0x3F800000u);
    unsigned long long bl = __ballot(ok);
    if (j == 0) sflag = (~bl == 0ull) ? 0 : 1;   // 1 = byte mask
  }
  for (int dd = j; dd < 512; dd += 256)
    cw[dd] = make_float2(E[bx * 512 + dd], -2.f * Wl[dd]);
  __syncthreads();

  const float* g = G + (bx >> 8) * 131072 + j * 4;
  float a0 = 0.f, a1 = 0.f, a2 = 0.f, a3 = 0.f;
#pragma unroll 8
  for (int db = 0; db < 128; ++db) {
    float4 v = *(const float4*)(g + db * 1024);
    float2 p0 = cw[db * 4 + 0], p1 = cw[db * 4 + 1];
    float2 p2 = cw[db * 4 + 2], p3 = cw[db * 4 + 3];
    a0 += p0.y * RCP(__builtin_fmaf(p0.x, v.x, 1.f));
    a1 += p1.y * RCP(__builtin_fmaf(p1.x, v.y, 1.f));
    a2 += p2.y * RCP(__builtin_fmaf(p2.x, v.z, 1.f));
    a3 += p3.y * RCP(__builtin_fmaf(p3.x, v.w, 1.f));
  }
  float l = (a0 + a1) + (a2 + a3);

  const int midx = bx * 256 + j;
  const int mv = sflag ? (int)((const unsigned char*)maskp)[midx]
                       : ((const int*)maskp)[midx];
  const bool msk = (mv != 0);
  const int any = __syncthreads_or(msk ? 1 : 0);
  const bool use = msk || (any == 0);   // fully-masked row -> unmask all

  float p = use ? EXP2(l * LOG2E) : 0.f;
  float s = p;
#pragma unroll
  for (int o = 32; o > 0; o >>= 1) s += __shfl_xor(s, o);
  if ((j & 63) == 0) red[j >> 6] = s;
  __syncthreads();
  const float S = (red[0] + red[1]) + (red[2] + red[3]);

  out[midx] = p * RCP(S);
}

extern "C" void kernel_launch(void* const* d_in, const int* in_sizes, int n_in,
                              void* d_out, int out_size, void* d_ws, size_t ws_size,
                              hipStream_t stream) {
  const float* key   = (const float*)d_in[0];
  const float* query = (const float*)d_in[1];
  // d_in[2] (value), d_in[6] (W_v), d_in[7] (b_v), d_in[13] (b_l) unused.
  const void*  mask  = d_in[3];
  const float* W_k   = (const float*)d_in[4];
  const float* b_k   = (const float*)d_in[5];
  const float* W_q   = (const float*)d_in[8];
  const float* b_q   = (const float*)d_in[9];
  const float* W_c   = (const float*)d_in[10];
  const float* b_c   = (const float*)d_in[11];
  const float* W_l   = (const float*)d_in[12];

  float* ws = (float*)d_ws;
  float* q2 = ws;             // [512][512] f32: (query@Wq.T+bq)/sqrt(D)
  float* k2 = ws + 262144;    // [512][512] f32: key@Wk.T+bk
  float* E  = ws + 524288;    // [512][512] f32: exp2(C*(aq+bc)), row = b*256+i
  float* G  = ws + 786432;    // [2][128][256][4] f32: exp2(C*ak), d-interleaved

  dim3 g(16, 8, 2);
  gemm_bt<<<g, 256, 0, stream>>>(query, W_q, b_q, INV_SQRTD, q2, 0, 512, 0,
                                 key,   W_k, b_k, 1.0f,      k2, 0, 512, 0);
  gemm_bt<<<g, 256, 0, stream>>>(q2, W_c,       b_c,     TWO_LOG2E, E, 0, 1024, 1,
                                 k2, W_c + 512, nullptr, TWO_LOG2E, G, 1, 1024, 1);
  attn_sm<<<512, 256, 0, stream>>>(E, G, mask, W_l, (float*)d_out);
}